// Round 6
// baseline (485.498 us; speedup 1.0000x reference)
//
#include <hip/hip_runtime.h>
#include <hip/hip_bf16.h>

#define D_MODEL 1024
#define D_INNER 2048
#define NTOK    16384   // B*T = 4*4096
#define TLEN    4096
#define LN_EPS  1e-5f

typedef unsigned short u16;
typedef unsigned short u16x4 __attribute__((ext_vector_type(4)));
typedef unsigned short u16x8 __attribute__((ext_vector_type(8)));
typedef __bf16        bf16x8 __attribute__((ext_vector_type(8)));
typedef float         f32x4  __attribute__((ext_vector_type(4)));
typedef float         f32x16 __attribute__((ext_vector_type(16)));

__device__ __forceinline__ float b2f(u16 u) {
    union { float f; unsigned int i; } v; v.i = ((unsigned int)u) << 16; return v.f;
}
__device__ __forceinline__ u16 f2b(float f) {
    union { float f; unsigned int i; } v; v.f = f;
    unsigned int r = v.i + 0x7fffu + ((v.i >> 16) & 1u);  // RNE
    return (u16)(r >> 16);
}

// async global->LDS, 16B per lane. LDS dest = wave-uniform base + lane*16.
__device__ __forceinline__ void gld_lds16(const u16* g, u16* l) {
    __builtin_amdgcn_global_load_lds(
        (const __attribute__((address_space(1))) void*)g,
        (__attribute__((address_space(3))) void*)l, 16, 0, 0);
}

// ---------------- fp32 -> bf16 bulk convert (weights) ----------------
__global__ __launch_bounds__(256) void cvt_f32_bf16(
    const float* __restrict__ src, u16* __restrict__ dst, int n)
{
    const int i = blockIdx.x * 256 + threadIdx.x;
    const int o = i * 4;
    if (o < n) {
        f32x4 v = *(const f32x4*)(src + o);
        u16x4 w;
#pragma unroll
        for (int j = 0; j < 4; j++) w[j] = f2b(v[j]);
        *(u16x4*)(dst + o) = w;
    }
}

// ---------------- conv_w [2048][4] -> wt [4][2048] fp32 transpose ----------------
__global__ __launch_bounds__(256) void cvt_convw(
    const float* __restrict__ w, float* __restrict__ wt)
{
    const int i = blockIdx.x * 256 + threadIdx.x;   // 0..8191
    const int ch = i >> 2, j = i & 3;
    wt[j * D_INNER + ch] = w[i];
}

// ---------------- LayerNorm (fp32 in, bf16 out): one block per row ----------------
__global__ __launch_bounds__(256) void ln_kernel(
    const float* __restrict__ x, const float* __restrict__ gamma,
    const float* __restrict__ beta, u16* __restrict__ xn)
{
    const int row = blockIdx.x;
    const int tid = threadIdx.x;
    const float* xr = x + (size_t)row * D_MODEL;
    const int c0 = tid * 4;

    f32x4 xv = *(const f32x4*)(xr + c0);
    float s = 0.f, s2 = 0.f;
#pragma unroll
    for (int i = 0; i < 4; i++) { s += xv[i]; s2 += xv[i] * xv[i]; }

#pragma unroll
    for (int off = 32; off > 0; off >>= 1) {
        s  += __shfl_down(s,  off);
        s2 += __shfl_down(s2, off);
    }
    __shared__ float red[8];
    const int wave = tid >> 6, lane = tid & 63;
    if (lane == 0) { red[wave] = s; red[4 + wave] = s2; }
    __syncthreads();
    const float ts  = red[0] + red[1] + red[2] + red[3];
    const float ts2 = red[4] + red[5] + red[6] + red[7];
    const float mu  = ts * (1.0f / D_MODEL);
    const float var = ts2 * (1.0f / D_MODEL) - mu * mu;
    const float inv = rsqrtf(var + LN_EPS);

    f32x4 gv = *(const f32x4*)(gamma + c0);
    f32x4 bv = *(const f32x4*)(beta + c0);
    u16x4 out;
#pragma unroll
    for (int i = 0; i < 4; i++)
        out[i] = f2b((xv[i] - mu) * inv * gv[i] + bv[i]);
    *(u16x4*)(xn + (size_t)row * D_MODEL + c0) = out;
}

// ---------------- GEMM C[M,N] = A[M,K] * Bt[N,K]^T (+fp32 residual) ----------------
// 128x128 tile, BK=64, 4 waves 2x2 (64x64 each), 32x32x16 MFMA (2x2 subtiles).
// global_load_lds width-16 staging with XOR-swizzled LDS layout:
// LDS[row][chunk] = G[row][chunk^(row&7)] (swizzle on SOURCE address; LDS dest
// is lane-pinned). Fragment reads use chunk=((2ks+half)^(lane&7)) so each
// consecutive-8-lane group covers 8 distinct 16B chunks -> conflict-free b128.
template<bool OUT_F32>
__global__ __launch_bounds__(256) void gemm_bt(
    const u16* __restrict__ A, const u16* __restrict__ Bt,
    void* __restrict__ Cv, const float* __restrict__ Res,
    int M, int N, int K)
{
    __shared__ u16 As[128 * 64];
    __shared__ u16 Bs[128 * 64];

    const int tid  = threadIdx.x;
    const int bm   = blockIdx.x;
    const int bn   = blockIdx.y;
    const int wave = tid >> 6;
    const int lane = tid & 63;
    const int wm = wave >> 1, wn = wave & 1;
    const int l31  = lane & 31;
    const int half = lane >> 5;          // 0/1: which K-half of the fragment
    const int l7   = lane & 7;

    f32x16 acc[2][2] = {};

    const u16* Ag = A  + (size_t)bm * 128 * K;
    const u16* Bg = Bt + (size_t)bn * 128 * K;

    const int lrow = lane >> 3;                   // 0..7 row within 8-row slab
    const int lcol = ((lane & 7) ^ lrow) * 8;     // swizzled source chunk

    for (int kt = 0; kt < K; kt += 64) {
#pragma unroll
        for (int p = 0; p < 4; p++) {
            const int r = p * 32 + wave * 8;      // wave-uniform slab base
            gld_lds16(Ag + (size_t)(r + lrow) * K + kt + lcol, &As[r * 64]);
            gld_lds16(Bg + (size_t)(r + lrow) * K + kt + lcol, &Bs[r * 64]);
        }
        __syncthreads();

#pragma unroll
        for (int ks = 0; ks < 4; ks++) {          // K-step of 16
            const int chunk = ((ks * 2 + half) ^ l7) * 8;
            bf16x8 af[2], bfr[2];
#pragma unroll
            for (int t = 0; t < 2; t++) {
                af[t]  = __builtin_bit_cast(bf16x8,
                    *(const u16x8*)(&As[(wm * 64 + t * 32 + l31) * 64 + chunk]));
                bfr[t] = __builtin_bit_cast(bf16x8,
                    *(const u16x8*)(&Bs[(wn * 64 + t * 32 + l31) * 64 + chunk]));
            }
#pragma unroll
            for (int tm = 0; tm < 2; tm++)
#pragma unroll
                for (int tn = 0; tn < 2; tn++)
                    acc[tm][tn] = __builtin_amdgcn_mfma_f32_32x32x16_bf16(
                        af[tm], bfr[tn], acc[tm][tn], 0, 0, 0);
        }
        __syncthreads();
    }

    // Epilogue (32x32 C/D, HW-verified m74/m101):
    // col = lane&31, row = (reg&3) + 8*(reg>>2) + 4*(lane>>5)
    const int m0 = bm * 128 + wm * 64;
    const int n0 = bn * 128 + wn * 64 + l31;
    const int rb = half * 4;
#pragma unroll
    for (int tm = 0; tm < 2; tm++) {
#pragma unroll
        for (int tn = 0; tn < 2; tn++) {
#pragma unroll
            for (int reg = 0; reg < 16; reg++) {
                const int r  = m0 + tm * 32 + rb + (reg & 3) + 8 * (reg >> 2);
                const int cc = n0 + tn * 32;
                const size_t idx = (size_t)r * N + cc;
                float v = acc[tm][tn][reg];
                if (OUT_F32) {
                    ((float*)Cv)[idx] = v + Res[idx];
                } else {
                    ((u16*)Cv)[idx] = f2b(v);
                }
            }
        }
    }
}

// ---------------- causal depthwise conv (d_conv=4) + silu(x)*silu(z) ----------------
// 4 tokens per thread; wt is transposed [4][2048] fp32 -> coalesced loads.
__global__ __launch_bounds__(256) void conv_gate4(
    const u16* __restrict__ xz, const float* __restrict__ wt,
    const float* __restrict__ conv_b, u16* __restrict__ y)
{
    const int tid  = threadIdx.x;
    const int row0 = blockIdx.x * 4;          // first token row of this block
    const int c    = tid * 8;                 // channel base
    const int t0   = row0 & (TLEN - 1);       // within-sequence position

    float w[4][8];
#pragma unroll
    for (int j = 0; j < 4; j++) {
        f32x4 a = *(const f32x4*)(wt + j * D_INNER + c);
        f32x4 b = *(const f32x4*)(wt + j * D_INNER + c + 4);
#pragma unroll
        for (int u = 0; u < 4; u++) { w[j][u] = a[u]; w[j][4 + u] = b[u]; }
    }
    float bias[8];
    {
        f32x4 a = *(const f32x4*)(conv_b + c);
        f32x4 b = *(const f32x4*)(conv_b + c + 4);
#pragma unroll
        for (int u = 0; u < 4; u++) { bias[u] = a[u]; bias[4 + u] = b[u]; }
    }

    u16x8 xv[7];
    if (t0 != 0) {
#pragma unroll
        for (int k = 0; k < 3; k++)
            xv[k] = *(const u16x8*)(xz + (size_t)(row0 - 3 + k) * 4096 + c);
    } else {
#pragma unroll
        for (int k = 0; k < 3; k++) xv[k] = (u16x8)0;
    }
#pragma unroll
    for (int k = 3; k < 7; k++)
        xv[k] = *(const u16x8*)(xz + (size_t)(row0 - 3 + k) * 4096 + c);

#pragma unroll
    for (int i = 0; i < 4; i++) {             // output tokens row0+i
        float acc[8];
#pragma unroll
        for (int u = 0; u < 8; u++) acc[u] = bias[u];
#pragma unroll
        for (int j = 0; j < 4; j++)           // tap j uses x[t-3+j] = xv[i+j]
#pragma unroll
            for (int u = 0; u < 8; u++)
                acc[u] += b2f(xv[i + j][u]) * w[j][u];

        u16x8 zv = *(const u16x8*)(xz + (size_t)(row0 + i) * 4096 + 2048 + c);
        u16x8 out;
#pragma unroll
        for (int u = 0; u < 8; u++) {
            const float a = acc[u];
            const float z = b2f(zv[u]);
            const float sa = a / (1.0f + __expf(-a));
            const float sz = z / (1.0f + __expf(-z));
            out[u] = f2b(sa * sz);
        }
        *(u16x8*)(y + (size_t)(row0 + i) * (size_t)D_INNER + c) = out;
    }
}

extern "C" void kernel_launch(void* const* d_in, const int* in_sizes, int n_in,
                              void* d_out, int out_size, void* d_ws, size_t ws_size,
                              hipStream_t stream)
{
    const float* x      = (const float*)d_in[0];
    const float* gamma  = (const float*)d_in[1];
    const float* beta   = (const float*)d_in[2];
    const float* W_in   = (const float*)d_in[3];  // [4096, 1024] fp32
    const float* conv_w = (const float*)d_in[4];  // [2048, 1, 4] fp32
    const float* conv_b = (const float*)d_in[5];  // [2048] fp32
    const float* W_out  = (const float*)d_in[6];  // [1024, 2048] fp32
    float* out = (float*)d_out;

    const int nWin  = 4096 * 1024;
    const int nWout = 1024 * 2048;
    const int nWc   = D_INNER * 4;            // 8192

    u16*   wbin  = (u16*)d_ws;                // bf16 W_in
    u16*   wbout = wbin + nWin;               // bf16 W_out
    float* wt    = (float*)(wbout + nWout);   // fp32 [4][2048] conv weights
    u16*   base  = (u16*)(wt + nWc);

    // Workspace-adaptive chunking (whole batches -> conv halo never crosses).
    const size_t wbytes = (size_t)(nWin + nWout) * sizeof(u16) + nWc * sizeof(float);
    const size_t perRow = (size_t)(D_MODEL + 4096 + D_INNER) * sizeof(u16);
    int NC = 4;
    if (ws_size >= wbytes + (size_t)NTOK * perRow)          NC = 1;
    else if (ws_size >= wbytes + (size_t)(NTOK/2) * perRow) NC = 2;
    const int RC = NTOK / NC;

    u16* xn = base;                               // RC*1024
    u16* xz = xn + (size_t)RC * D_MODEL;          // RC*4096
    u16* y  = xz + (size_t)RC * 4096;             // RC*2048

    // 0. weight preprocessing (same work every call)
    cvt_f32_bf16<<<(nWin / 4 + 255) / 256, 256, 0, stream>>>(W_in, wbin, nWin);
    cvt_f32_bf16<<<(nWout / 4 + 255) / 256, 256, 0, stream>>>(W_out, wbout, nWout);
    cvt_convw<<<nWc / 256, 256, 0, stream>>>(conv_w, wt);

    for (int c = 0; c < NC; c++) {
        const float* xc   = x   + (size_t)c * RC * D_MODEL;
        float*       outc = out + (size_t)c * RC * D_MODEL;

        // 1. LayerNorm
        ln_kernel<<<RC, 256, 0, stream>>>(xc, gamma, beta, xn);

        // 2. in_proj: xz[RC,4096] = xn[RC,1024] @ W_in^T  (bf16 out)
        dim3 g1(RC / 128, 4096 / 128);
        gemm_bt<false><<<g1, 256, 0, stream>>>(xn, wbin, xz, nullptr,
                                               RC, 2 * D_INNER, D_MODEL);

        // 3. causal depthwise conv + silu gating (4 tokens/thread)
        conv_gate4<<<RC / 4, 256, 0, stream>>>(xz, wt, conv_b, y);

        // 4. out_proj + residual: out[RC,1024] = x + y[RC,2048] @ W_out^T (fp32 out)
        dim3 g2(RC / 128, D_MODEL / 128);
        gemm_bt<true><<<g2, 256, 0, stream>>>(y, wbout, outc, xc,
                                              RC, D_MODEL, D_INNER);
    }
}

// Round 7
// 434.914 us; speedup vs baseline: 1.1163x; 1.1163x over previous
//
#include <hip/hip_runtime.h>
#include <hip/hip_bf16.h>

#define D_MODEL 1024
#define D_INNER 2048
#define NTOK    16384   // B*T = 4*4096
#define TLEN    4096
#define LN_EPS  1e-5f

typedef unsigned short u16;
typedef unsigned short u16x4 __attribute__((ext_vector_type(4)));
typedef unsigned short u16x8 __attribute__((ext_vector_type(8)));
typedef __bf16        bf16x8 __attribute__((ext_vector_type(8)));
typedef float         f32x4  __attribute__((ext_vector_type(4)));

__device__ __forceinline__ float b2f(u16 u) {
    union { float f; unsigned int i; } v; v.i = ((unsigned int)u) << 16; return v.f;
}
__device__ __forceinline__ u16 f2b(float f) {
    union { float f; unsigned int i; } v; v.f = f;
    unsigned int r = v.i + 0x7fffu + ((v.i >> 16) & 1u);  // RNE
    return (u16)(r >> 16);
}

// async global->LDS, 16B per lane. LDS dest = wave-uniform base + lane*16.
__device__ __forceinline__ void gld_lds16(const u16* g, u16* l) {
    __builtin_amdgcn_global_load_lds(
        (const __attribute__((address_space(1))) void*)g,
        (__attribute__((address_space(3))) void*)l, 16, 0, 0);
}

// ---------------- LayerNorm body (fp32 in, bf16 out), one block per row ----------------
__device__ __forceinline__ void ln_body(
    int row, int tid,
    const float* __restrict__ x, const float* __restrict__ gamma,
    const float* __restrict__ beta, u16* __restrict__ xn)
{
    const float* xr = x + (size_t)row * D_MODEL;
    const int c0 = tid * 4;

    f32x4 xv = *(const f32x4*)(xr + c0);
    float s = 0.f, s2 = 0.f;
#pragma unroll
    for (int i = 0; i < 4; i++) { s += xv[i]; s2 += xv[i] * xv[i]; }

#pragma unroll
    for (int off = 32; off > 0; off >>= 1) {
        s  += __shfl_down(s,  off);
        s2 += __shfl_down(s2, off);
    }
    __shared__ float red[8];
    const int wave = tid >> 6, lane = tid & 63;
    if (lane == 0) { red[wave] = s; red[4 + wave] = s2; }
    __syncthreads();
    const float ts  = red[0] + red[1] + red[2] + red[3];
    const float ts2 = red[4] + red[5] + red[6] + red[7];
    const float mu  = ts * (1.0f / D_MODEL);
    const float var = ts2 * (1.0f / D_MODEL) - mu * mu;
    const float inv = rsqrtf(var + LN_EPS);

    f32x4 gv = *(const f32x4*)(gamma + c0);
    f32x4 bv = *(const f32x4*)(beta + c0);
    u16x4 out;
#pragma unroll
    for (int i = 0; i < 4; i++)
        out[i] = f2b((xv[i] - mu) * inv * gv[i] + bv[i]);
    *(u16x4*)(xn + (size_t)row * D_MODEL + c0) = out;
}

// ---------------- merged prep: LN (lnRows rows) + W cvt + conv_w transpose ----------------
// Block partition (wave-uniform branch):
//   [0, lnRows)                 : LayerNorm row = blockIdx.x
//   [lnRows, +4096)             : W_in fp32->bf16   (4.19M elems, 4/thread)
//   [.., +2048)                 : W_out fp32->bf16  (2.10M elems, 4/thread)
//   [.., +32)                   : conv_w [2048][4] -> wt [4][2048]
__global__ __launch_bounds__(256) void prep_kernel(
    const float* __restrict__ x, const float* __restrict__ gamma,
    const float* __restrict__ beta, u16* __restrict__ xn,
    const float* __restrict__ W_in, u16* __restrict__ wbin,
    const float* __restrict__ W_out, u16* __restrict__ wbout,
    const float* __restrict__ conv_w, float* __restrict__ wt,
    int lnRows)
{
    const int b   = blockIdx.x;
    const int tid = threadIdx.x;

    if (b < lnRows) {
        ln_body(b, tid, x, gamma, beta, xn);
        return;
    }
    int rb = b - lnRows;
    if (rb < 4096) {                       // W_in convert
        const int o = (rb * 256 + tid) * 4;
        f32x4 v = *(const f32x4*)(W_in + o);
        u16x4 w;
#pragma unroll
        for (int j = 0; j < 4; j++) w[j] = f2b(v[j]);
        *(u16x4*)(wbin + o) = w;
        return;
    }
    rb -= 4096;
    if (rb < 2048) {                       // W_out convert
        const int o = (rb * 256 + tid) * 4;
        f32x4 v = *(const f32x4*)(W_out + o);
        u16x4 w;
#pragma unroll
        for (int j = 0; j < 4; j++) w[j] = f2b(v[j]);
        *(u16x4*)(wbout + o) = w;
        return;
    }
    rb -= 2048;                            // conv_w transpose (32 blocks)
    const int i = rb * 256 + tid;          // 0..8191
    const int ch = i >> 2, j = i & 3;
    wt[j * D_INNER + ch] = conv_w[i];
}

// ---------------- standalone LN (chunked fallback path) ----------------
__global__ __launch_bounds__(256) void ln_kernel(
    const float* __restrict__ x, const float* __restrict__ gamma,
    const float* __restrict__ beta, u16* __restrict__ xn)
{
    ln_body(blockIdx.x, threadIdx.x, x, gamma, beta, xn);
}

// ---------------- GEMM C[M,N] = A[M,K] * Bt[N,K]^T (+fp32 residual) ----------------
// R5-verified: 128x128 tile, BK=64, 4 waves 2x2 (64x64), 16x16x32 MFMA.
// global_load_lds width-16 staging, XOR-swizzled source so
// LDS[row][chunk] = G[row][chunk^(row&7)]; fragment reads conflict-free.
template<bool OUT_F32>
__global__ __launch_bounds__(256) void gemm_bt(
    const u16* __restrict__ A, const u16* __restrict__ Bt,
    void* __restrict__ Cv, const float* __restrict__ Res,
    int M, int N, int K)
{
    __shared__ u16 As[128 * 64];
    __shared__ u16 Bs[128 * 64];

    const int tid  = threadIdx.x;
    const int bm   = blockIdx.x;
    const int bn   = blockIdx.y;
    const int wave = tid >> 6;
    const int lane = tid & 63;
    const int wm = wave >> 1, wn = wave & 1;
    const int lane15 = lane & 15, quad = lane >> 4;

    f32x4 acc[4][4] = {};

    const u16* Ag = A  + (size_t)bm * 128 * K;
    const u16* Bg = Bt + (size_t)bn * 128 * K;

    const int lrow = lane >> 3;                   // 0..7 row within 8-row slab
    const int lcol = ((lane & 7) ^ lrow) * 8;     // swizzled source chunk

    const int sw = lane15 & 7;                    // fragment-read swizzle key

    for (int kt = 0; kt < K; kt += 64) {
#pragma unroll
        for (int p = 0; p < 4; p++) {
            const int r = p * 32 + wave * 8;      // wave-uniform slab base
            gld_lds16(Ag + (size_t)(r + lrow) * K + kt + lcol, &As[r * 64]);
            gld_lds16(Bg + (size_t)(r + lrow) * K + kt + lcol, &Bs[r * 64]);
        }
        __syncthreads();

#pragma unroll
        for (int kk = 0; kk < 64; kk += 32) {
            const int chunk = (((kk >> 3) + quad) ^ sw) * 8;
            bf16x8 af[4], bfr[4];
#pragma unroll
            for (int t = 0; t < 4; t++) {
                af[t]  = __builtin_bit_cast(bf16x8,
                    *(const u16x8*)(&As[(wm * 64 + t * 16 + lane15) * 64 + chunk]));
                bfr[t] = __builtin_bit_cast(bf16x8,
                    *(const u16x8*)(&Bs[(wn * 64 + t * 16 + lane15) * 64 + chunk]));
            }
#pragma unroll
            for (int tm = 0; tm < 4; tm++)
#pragma unroll
                for (int tn = 0; tn < 4; tn++)
                    acc[tm][tn] = __builtin_amdgcn_mfma_f32_16x16x32_bf16(
                        af[tm], bfr[tn], acc[tm][tn], 0, 0, 0);
        }
        __syncthreads();
    }

    // Epilogue: C[row = quad*4+i][col = lane15] per 16x16 subtile
    const int m0 = bm * 128 + wm * 64 + quad * 4;
    const int n0 = bn * 128 + wn * 64 + lane15;
#pragma unroll
    for (int tm = 0; tm < 4; tm++) {
#pragma unroll
        for (int tn = 0; tn < 4; tn++) {
#pragma unroll
            for (int i = 0; i < 4; i++) {
                const int r  = m0 + tm * 16 + i;
                const int cc = n0 + tn * 16;
                const size_t idx = (size_t)r * N + cc;
                float v = acc[tm][tn][i];
                if (OUT_F32) {
                    ((float*)Cv)[idx] = v + Res[idx];
                } else {
                    ((u16*)Cv)[idx] = f2b(v);
                }
            }
        }
    }
}

// ---------------- causal depthwise conv (d_conv=4) + silu(x)*silu(z) ----------------
// 8 tokens per thread (4096%8==0 so a strip never crosses a sequence start).
// wt is transposed [4][2048] fp32 -> coalesced loads.
__global__ __launch_bounds__(256) void conv_gate8(
    const u16* __restrict__ xz, const float* __restrict__ wt,
    const float* __restrict__ conv_b, u16* __restrict__ y)
{
    const int tid  = threadIdx.x;
    const int row0 = blockIdx.x * 8;          // first token row of this strip
    const int c    = tid * 8;                 // channel base
    const int t0   = row0 & (TLEN - 1);       // within-sequence position

    float w[4][8];
#pragma unroll
    for (int j = 0; j < 4; j++) {
        f32x4 a = *(const f32x4*)(wt + j * D_INNER + c);
        f32x4 b = *(const f32x4*)(wt + j * D_INNER + c + 4);
#pragma unroll
        for (int u = 0; u < 4; u++) { w[j][u] = a[u]; w[j][4 + u] = b[u]; }
    }
    float bias[8];
    {
        f32x4 a = *(const f32x4*)(conv_b + c);
        f32x4 b = *(const f32x4*)(conv_b + c + 4);
#pragma unroll
        for (int u = 0; u < 4; u++) { bias[u] = a[u]; bias[4 + u] = b[u]; }
    }

    u16x8 xv[11];                             // rows row0-3 .. row0+7
    if (t0 != 0) {
#pragma unroll
        for (int k = 0; k < 3; k++)
            xv[k] = *(const u16x8*)(xz + (size_t)(row0 - 3 + k) * 4096 + c);
    } else {
#pragma unroll
        for (int k = 0; k < 3; k++) xv[k] = (u16x8)0;
    }
#pragma unroll
    for (int k = 3; k < 11; k++)
        xv[k] = *(const u16x8*)(xz + (size_t)(row0 - 3 + k) * 4096 + c);

#pragma unroll
    for (int i = 0; i < 8; i++) {             // output tokens row0+i
        float acc[8];
#pragma unroll
        for (int u = 0; u < 8; u++) acc[u] = bias[u];
#pragma unroll
        for (int j = 0; j < 4; j++)           // tap j uses x[t-3+j] = xv[i+j]
#pragma unroll
            for (int u = 0; u < 8; u++)
                acc[u] += b2f(xv[i + j][u]) * w[j][u];

        u16x8 zv = *(const u16x8*)(xz + (size_t)(row0 + i) * 4096 + 2048 + c);
        u16x8 out;
#pragma unroll
        for (int u = 0; u < 8; u++) {
            const float a = acc[u];
            const float z = b2f(zv[u]);
            const float sa = a / (1.0f + __expf(-a));
            const float sz = z / (1.0f + __expf(-z));
            out[u] = f2b(sa * sz);
        }
        *(u16x8*)(y + (size_t)(row0 + i) * (size_t)D_INNER + c) = out;
    }
}

extern "C" void kernel_launch(void* const* d_in, const int* in_sizes, int n_in,
                              void* d_out, int out_size, void* d_ws, size_t ws_size,
                              hipStream_t stream)
{
    const float* x      = (const float*)d_in[0];
    const float* gamma  = (const float*)d_in[1];
    const float* beta   = (const float*)d_in[2];
    const float* W_in   = (const float*)d_in[3];  // [4096, 1024] fp32
    const float* conv_w = (const float*)d_in[4];  // [2048, 1, 4] fp32
    const float* conv_b = (const float*)d_in[5];  // [2048] fp32
    const float* W_out  = (const float*)d_in[6];  // [1024, 2048] fp32
    float* out = (float*)d_out;

    const int nWin  = 4096 * 1024;
    const int nWout = 1024 * 2048;
    const int nWc   = D_INNER * 4;            // 8192

    u16*   wbin  = (u16*)d_ws;                // bf16 W_in
    u16*   wbout = wbin + nWin;               // bf16 W_out
    float* wt    = (float*)(wbout + nWout);   // fp32 [4][2048] conv weights
    u16*   base  = (u16*)(wt + nWc);

    // Workspace-adaptive chunking (whole batches -> conv halo never crosses).
    const size_t wbytes = (size_t)(nWin + nWout) * sizeof(u16) + nWc * sizeof(float);
    const size_t perRow = (size_t)(D_MODEL + 4096 + D_INNER) * sizeof(u16);
    int NC = 4;
    if (ws_size >= wbytes + (size_t)NTOK * perRow)          NC = 1;
    else if (ws_size >= wbytes + (size_t)(NTOK/2) * perRow) NC = 2;
    const int RC = NTOK / NC;

    u16* xn = base;                               // RC*1024
    u16* xz = xn + (size_t)RC * D_MODEL;          // RC*4096
    u16* y  = xz + (size_t)RC * 4096;             // RC*2048

    // 0. merged prep: weight cvt (+ full LN when NC==1) — one launch
    const int lnRows = (NC == 1) ? NTOK : 0;
    prep_kernel<<<lnRows + 4096 + 2048 + 32, 256, 0, stream>>>(
        x, gamma, beta, xn, W_in, wbin, W_out, wbout, conv_w, wt, lnRows);

    for (int c = 0; c < NC; c++) {
        const float* xc   = x   + (size_t)c * RC * D_MODEL;
        float*       outc = out + (size_t)c * RC * D_MODEL;

        // 1. LayerNorm (only needed per-chunk when NC>1)
        if (NC > 1)
            ln_kernel<<<RC, 256, 0, stream>>>(xc, gamma, beta, xn);

        // 2. in_proj: xz[RC,4096] = xn[RC,1024] @ W_in^T  (bf16 out)
        dim3 g1(RC / 128, 4096 / 128);
        gemm_bt<false><<<g1, 256, 0, stream>>>(xn, wbin, xz, nullptr,
                                               RC, 2 * D_INNER, D_MODEL);

        // 3. causal depthwise conv + silu gating (8 tokens/thread)
        conv_gate8<<<RC / 8, 256, 0, stream>>>(xz, wt, conv_b, y);

        // 4. out_proj + residual: out[RC,1024] = x + y[RC,2048] @ W_out^T (fp32 out)
        dim3 g2(RC / 128, D_MODEL / 128);
        gemm_bt<true><<<g2, 256, 0, stream>>>(y, wbout, outc, xc,
                                              RC, D_MODEL, D_INNER);
    }
}